// Round 2
// baseline (150.223 us; speedup 1.0000x reference)
//
#include <hip/hip_runtime.h>
#include <hip/hip_bf16.h>
#include <stdint.h>

// Problem constants
#define NN 4096
#define SLOPE 0.2f
#define LOG2E 1.44269504088896340736f

typedef float f32x4 __attribute__((ext_vector_type(4)));
typedef float f32x2 __attribute__((ext_vector_type(2)));
typedef short s16x8 __attribute__((ext_vector_type(8)));
typedef unsigned u32x4 __attribute__((ext_vector_type(4)));

static __device__ __forceinline__ unsigned f32_to_bf16_rne(float f) {
    unsigned u = __builtin_bit_cast(unsigned, f);
    return (u + 0x7FFFu + ((u >> 16) & 1u)) >> 16;
}

// ---------------------------------------------------------------------------
// K0: adjacency -> bitmask (N*N/32 dwords = 2 MB), with on-device dtype
// detection. numpy-bool upload (1 B/elem) vs int32 upload (4 B/elem): if the
// first 32 dwords are all <= 1 the buffer must be int32 (a bool-byte buffer
// has random 0/1 in the high 3 bytes of each dword; P(all zero) = 2^-96).
// Word o covers flat elements [o*32, o*32+32); bit b = element o*32+b.
// ---------------------------------------------------------------------------
__global__ __launch_bounds__(256) void k0_pack(const unsigned* __restrict__ src,
                                               unsigned* __restrict__ bits) {
    __shared__ int s_i32;
    const int t = threadIdx.x;
    if (t == 0) {
        int all_small = 1;
        for (int i = 0; i < 32; ++i) all_small &= (src[i] <= 1u);
        s_i32 = all_small;
    }
    __syncthreads();
    const long o = (long)blockIdx.x * 256 + t;  // word index, < 524288
    unsigned m = 0;
    if (s_i32) {
        const u32x4* p = (const u32x4*)src + o * 8;  // 32 ints
        #pragma unroll
        for (int g = 0; g < 8; ++g) {
            u32x4 v = p[g];
            m |= (v.x & 1u) << (g * 4) | (v.y & 1u) << (g * 4 + 1) |
                 (v.z & 1u) << (g * 4 + 2) | (v.w & 1u) << (g * 4 + 3);
        }
    } else {
        const u32x4* p = (const u32x4*)src + o * 2;  // 32 bytes
        #pragma unroll
        for (int g = 0; g < 2; ++g) {
            u32x4 v = p[g];
            unsigned d[4] = {v.x, v.y, v.z, v.w};
            #pragma unroll
            for (int q = 0; q < 4; ++q)
                #pragma unroll
                for (int b = 0; b < 4; ++b)
                    m |= ((d[q] >> (8 * b)) & 1u) << (g * 16 + q * 4 + b);
        }
    }
    bits[o] = m;
}

// ---------------------------------------------------------------------------
// K1: Wx = x @ W^T via bf16 MFMA (16 rows/block, grid=256).
// Emits:
//   wxb  : Wx in bf16, pre-tiled in MFMA B-fragment order:
//          [jblk(128)][fblk(8)][lane(64)][e(8)]  (j=row of Wx, f=col)
//   ai_s : alpha_i * log2e, layout [n][h]
//   ajT_s: alpha_j * log2e, layout [h][n]
// ---------------------------------------------------------------------------
__global__ __launch_bounds__(256) void k1_wx(const float* __restrict__ x,
                                             const float* __restrict__ W,
                                             const float* __restrict__ a,
                                             unsigned short* __restrict__ wxb,
                                             float* __restrict__ ai_s,
                                             float* __restrict__ ajT_s) {
    __shared__ unsigned short WL[128 * 136];  // W bf16, [c][k], pad 8
    __shared__ unsigned short XL[16 * 136];   // x tile bf16, [r][k], pad 8
    __shared__ float WxF[16 * 132];           // Wx fp32 for alpha dots

    const int t = threadIdx.x;
    const int i0 = blockIdx.x * 16;

    // stage W (128x128 fp32 -> bf16 pairs)
    for (int p = t; p < 8192; p += 256) {
        f32x2 w2 = *(const f32x2*)(W + 2 * p);
        unsigned lo = f32_to_bf16_rne(w2.x);
        unsigned hi = f32_to_bf16_rne(w2.y);
        int c = (2 * p) >> 7, k = (2 * p) & 127;
        *(unsigned*)&WL[c * 136 + k] = lo | (hi << 16);
    }
    // stage x tile (16x128)
    for (int p = t; p < 1024; p += 256) {
        f32x2 x2 = *(const f32x2*)(x + (long)i0 * 128 + 2 * p);
        unsigned lo = f32_to_bf16_rne(x2.x);
        unsigned hi = f32_to_bf16_rne(x2.y);
        int r = (2 * p) >> 7, k = (2 * p) & 127;
        *(unsigned*)&XL[r * 136 + k] = lo | (hi << 16);
    }
    __syncthreads();

    const int w = t >> 6, l = t & 63, m = l & 15, q = l >> 4;
    f32x4 acc0 = {0.f, 0.f, 0.f, 0.f}, acc1 = {0.f, 0.f, 0.f, 0.f};
    #pragma unroll
    for (int ks = 0; ks < 4; ++ks) {
        s16x8 af = *(const s16x8*)&XL[m * 136 + ks * 32 + q * 8];
        s16x8 b0 = *(const s16x8*)&WL[(w * 32 + m) * 136 + ks * 32 + q * 8];
        s16x8 b1 = *(const s16x8*)&WL[(w * 32 + 16 + m) * 136 + ks * 32 + q * 8];
        acc0 = __builtin_amdgcn_mfma_f32_16x16x32_bf16(af, b0, acc0, 0, 0, 0);
        acc1 = __builtin_amdgcn_mfma_f32_16x16x32_bf16(af, b1, acc1, 0, 0, 0);
    }
    // C/D layout: col = lane&15 (=m), row = q*4+reg.  Scatter into wxb + WxF.
    #pragma unroll
    for (int j2 = 0; j2 < 2; ++j2) {
        const int fblk = 2 * w + j2;
        f32x4 acc = j2 ? acc1 : acc0;
        #pragma unroll
        for (int reg = 0; reg < 4; ++reg) {
            float v = acc[reg];
            int row_g = i0 + q * 4 + reg;           // Wx row (K2's j index)
            int kl = row_g & 31, jblk = row_g >> 5;
            wxb[(((jblk * 8 + fblk) * 64 + (kl >> 3) * 16 + m) << 3) + (kl & 7)] =
                (unsigned short)f32_to_bf16_rne(v);
            WxF[(q * 4 + reg) * 132 + fblk * 16 + m] = v;
        }
    }
    __syncthreads();
    if (t < 64) {
        int r = t >> 2, h = t & 3;
        float s_i = 0.f, s_j = 0.f;
        const float* ar = a + h * 64;
        #pragma unroll
        for (int d = 0; d < 32; ++d) {
            float wv = WxF[r * 132 + h * 32 + d];
            s_i += wv * ar[d];
            s_j += wv * ar[32 + d];
        }
        ai_s[(i0 + r) * 4 + h] = s_i * LOG2E;
        ajT_s[h * NN + i0 + r] = s_j * LOG2E;
    }
}

// ---------------------------------------------------------------------------
// K2: flash-style masked softmax + PV + residual + LayerNorm.
// grid=256 blocks (16 rows each), 512 threads = 8 waves = (head h, k-parity p).
// Scores computed in registers directly in MFMA A-fragment layout; B-frags are
// coalesced global dwordx4 from wxb (L2-resident, 1 MB). No barriers in k-loop.
// Mask comes from the packed bitmask (1 dword per lane-step).
// ---------------------------------------------------------------------------
__global__ __launch_bounds__(512) void k2_attn(const float* __restrict__ x,
                                               const unsigned* __restrict__ adjbits,
                                               const unsigned short* __restrict__ wxb,
                                               const float* __restrict__ ai_s,
                                               const float* __restrict__ ajT_s,
                                               const float* __restrict__ gamma,
                                               const float* __restrict__ beta,
                                               float* __restrict__ out) {
    __shared__ float C_lds[4][16][32];
    __shared__ float l_lds[4][16];

    const int t = threadIdx.x;
    const int i0 = blockIdx.x * 16;
    const int w = t >> 6, l = t & 63;
    const int h = w & 3, p = w >> 2;
    const int m = l & 15, q = l >> 4;
    const int rg = i0 + m;

    const float ai = ai_s[rg * 4 + h];
    const unsigned* abp = adjbits + (long)rg * 128;   // 128 words per row
    const float* ajp = ajT_s + h * NN + q * 8;
    const unsigned short* bp = wxb + ((2 * h) * 64 + l) * 8;

    f32x4 acc0 = {0.f, 0.f, 0.f, 0.f}, acc1 = {0.f, 0.f, 0.f, 0.f};
    float lpart = 0.f;

    for (int ks = p; ks < 128; ks += 2) {   // 32 j per step; parity-split across wave pairs
        unsigned mq = (abp[ks] >> (q * 8)) & 0xffu;   // 8 mask bits for j = ks*32+q*8+e
        f32x4 aj0 = *(const f32x4*)(ajp + ks * 32);
        f32x4 aj1 = *(const f32x4*)(ajp + ks * 32 + 4);
        s16x8 b0 = *(const s16x8*)(bp + ks * 4096);
        s16x8 b1 = *(const s16x8*)(bp + ks * 4096 + 512);

        float ev[8];
        #pragma unroll
        for (int e = 0; e < 8; ++e) {
            float s = ai + (e < 4 ? aj0[e] : aj1[e - 4]);   // already * log2e
            s = fmaxf(s, SLOPE * s);                        // lrelu (scale-invariant)
            float ex = __builtin_amdgcn_exp2f(s);
            float msk = (float)((mq >> e) & 1u);            // 0.0 or 1.0
            ex *= msk;
            lpart += ex;
            ev[e] = ex;
        }
        union { s16x8 v; unsigned u[4]; } af;
        #pragma unroll
        for (int pr = 0; pr < 4; ++pr) {
            unsigned e0 = __builtin_bit_cast(unsigned, ev[2 * pr]);
            unsigned e1 = __builtin_bit_cast(unsigned, ev[2 * pr + 1]);
            af.u[pr] = __builtin_amdgcn_perm(e1, e0, 0x07060302);  // {hi16(e0), hi16(e1)}
        }
        acc0 = __builtin_amdgcn_mfma_f32_16x16x32_bf16(af.v, b0, acc0, 0, 0, 0);
        acc1 = __builtin_amdgcn_mfma_f32_16x16x32_bf16(af.v, b1, acc1, 0, 0, 0);
    }

    // row-sum l across the 4 quads (lanes l, l^16, l^32, l^48 share row m)
    lpart += __shfl_xor(lpart, 16, 64);
    lpart += __shfl_xor(lpart, 32, 64);

    if (p == 0) {
        #pragma unroll
        for (int reg = 0; reg < 4; ++reg) {
            C_lds[h][q * 4 + reg][m] = acc0[reg];
            C_lds[h][q * 4 + reg][16 + m] = acc1[reg];
        }
        if (l < 16) l_lds[h][l] = lpart;
    }
    __syncthreads();
    if (p == 1) {
        #pragma unroll
        for (int reg = 0; reg < 4; ++reg) {
            C_lds[h][q * 4 + reg][m] += acc0[reg];
            C_lds[h][q * 4 + reg][16 + m] += acc1[reg];
        }
        if (l < 16) l_lds[h][l] += lpart;
    }
    __syncthreads();

    // epilogue: normalize, residual, LayerNorm.  32 threads per row, 4 f each.
    {
        const int r = t >> 5, c32 = t & 31;
        const int f0 = c32 * 4;
        const int hh = f0 >> 5, cl = f0 & 31;
        const float linv = 1.0f / l_lds[hh][r];
        f32x4 xv = *(const f32x4*)(x + (long)(i0 + r) * 128 + f0);
        float y[4], s1 = 0.f, s2 = 0.f;
        #pragma unroll
        for (int kk = 0; kk < 4; ++kk) {
            float yy = C_lds[hh][r][cl + kk] * linv + xv[kk];
            y[kk] = yy; s1 += yy; s2 += yy * yy;
        }
        #pragma unroll
        for (int s = 1; s <= 16; s <<= 1) {
            s1 += __shfl_xor(s1, s, 64);
            s2 += __shfl_xor(s2, s, 64);
        }
        const float mean = s1 * (1.0f / 128.0f);
        const float var = s2 * (1.0f / 128.0f) - mean * mean;
        const float rstd = rsqrtf(var + 1e-5f);
        f32x4 gv = *(const f32x4*)(gamma + f0);
        f32x4 bv = *(const f32x4*)(beta + f0);
        f32x4 ov;
        #pragma unroll
        for (int kk = 0; kk < 4; ++kk)
            ov[kk] = gv[kk] * ((y[kk] - mean) * rstd) + bv[kk];
        *(f32x4*)(out + (long)(i0 + r) * 128 + f0) = ov;
    }
}

extern "C" void kernel_launch(void* const* d_in, const int* in_sizes, int n_in,
                              void* d_out, int out_size, void* d_ws, size_t ws_size,
                              hipStream_t stream) {
    const float* x = (const float*)d_in[0];
    const unsigned* adj_raw = (const unsigned*)d_in[1];  // bool-as-uint8 OR int32
    const float* W = (const float*)d_in[2];
    const float* a = (const float*)d_in[3];
    const float* gamma = (const float*)d_in[4];
    const float* beta = (const float*)d_in[5];

    unsigned short* wxb = (unsigned short*)d_ws;                        // 1 MB
    float* ai_s = (float*)((char*)d_ws + (1 << 20));                    // 64 KB
    float* ajT_s = (float*)((char*)d_ws + (1 << 20) + (64 << 10));      // 64 KB
    unsigned* adjbits = (unsigned*)((char*)d_ws + (2 << 20));           // 2 MB

    k0_pack<<<2048, 256, 0, stream>>>(adj_raw, adjbits);
    k1_wx<<<256, 256, 0, stream>>>(x, W, a, wxb, ai_s, ajT_s);
    k2_attn<<<256, 512, 0, stream>>>(x, adjbits, wxb, ai_s, ajT_s, gamma, beta,
                                     (float*)d_out);
}

// Round 3
// 136.391 us; speedup vs baseline: 1.1014x; 1.1014x over previous
//
#include <hip/hip_runtime.h>
#include <hip/hip_bf16.h>
#include <stdint.h>

// Problem constants
#define NN 4096
#define SLOPE 0.2f
#define LOG2E 1.44269504088896340736f

typedef float f32x4 __attribute__((ext_vector_type(4)));
typedef float f32x2 __attribute__((ext_vector_type(2)));
typedef short s16x8 __attribute__((ext_vector_type(8)));
typedef unsigned u32x4 __attribute__((ext_vector_type(4)));

static __device__ __forceinline__ unsigned f32_to_bf16_rne(float f) {
    unsigned u = __builtin_bit_cast(unsigned, f);
    return (u + 0x7FFFu + ((u >> 16) & 1u)) >> 16;
}

// ---------------------------------------------------------------------------
// K0: adjacency -> bitmask (N*N/32 dwords = 2 MB), with on-device dtype
// detection (verified working in R2: absmax passed). Word o covers flat
// elements [o*32, o*32+32); bit b = element o*32+b.
// ---------------------------------------------------------------------------
__global__ __launch_bounds__(256) void k0_pack(const unsigned* __restrict__ src,
                                               unsigned* __restrict__ bits) {
    __shared__ int s_i32;
    const int t = threadIdx.x;
    if (t == 0) {
        int all_small = 1;
        for (int i = 0; i < 32; ++i) all_small &= (src[i] <= 1u);
        s_i32 = all_small;
    }
    __syncthreads();
    const long o = (long)blockIdx.x * 256 + t;  // word index, < 524288
    unsigned m = 0;
    if (s_i32) {
        const u32x4* p = (const u32x4*)src + o * 8;  // 32 ints
        #pragma unroll
        for (int g = 0; g < 8; ++g) {
            u32x4 v = p[g];
            m |= (v.x & 1u) << (g * 4) | (v.y & 1u) << (g * 4 + 1) |
                 (v.z & 1u) << (g * 4 + 2) | (v.w & 1u) << (g * 4 + 3);
        }
    } else {
        const u32x4* p = (const u32x4*)src + o * 2;  // 32 bytes
        #pragma unroll
        for (int g = 0; g < 2; ++g) {
            u32x4 v = p[g];
            unsigned d[4] = {v.x, v.y, v.z, v.w};
            #pragma unroll
            for (int q = 0; q < 4; ++q)
                #pragma unroll
                for (int b = 0; b < 4; ++b)
                    m |= ((d[q] >> (8 * b)) & 1u) << (g * 16 + q * 4 + b);
        }
    }
    bits[o] = m;
}

// ---------------------------------------------------------------------------
// K1: Wx = x @ W^T via bf16 MFMA (16 rows/block, grid=256).  f32x4 staging.
// ---------------------------------------------------------------------------
__global__ __launch_bounds__(256) void k1_wx(const float* __restrict__ x,
                                             const float* __restrict__ W,
                                             const float* __restrict__ a,
                                             unsigned short* __restrict__ wxb,
                                             float* __restrict__ ai_s,
                                             float* __restrict__ ajT_s) {
    __shared__ unsigned short WL[128 * 136];  // W bf16, [c][k], pad 8
    __shared__ unsigned short XL[16 * 136];   // x tile bf16, [r][k], pad 8
    __shared__ float WxF[16 * 132];           // Wx fp32 for alpha dots

    const int t = threadIdx.x;
    const int i0 = blockIdx.x * 16;

    // stage W (128x128 fp32 -> bf16), 16 f32x4 per thread
    for (int p4 = t; p4 < 4096; p4 += 256) {
        f32x4 w4 = *(const f32x4*)(W + 4 * p4);
        unsigned lo = f32_to_bf16_rne(w4.x) | (f32_to_bf16_rne(w4.y) << 16);
        unsigned hi = f32_to_bf16_rne(w4.z) | (f32_to_bf16_rne(w4.w) << 16);
        int c = (4 * p4) >> 7, k = (4 * p4) & 127;
        *(unsigned long long*)&WL[c * 136 + k] =
            (unsigned long long)lo | ((unsigned long long)hi << 32);
    }
    // stage x tile (16x128), 2 f32x4 per thread
    for (int p4 = t; p4 < 512; p4 += 256) {
        f32x4 x4 = *(const f32x4*)(x + (long)i0 * 128 + 4 * p4);
        unsigned lo = f32_to_bf16_rne(x4.x) | (f32_to_bf16_rne(x4.y) << 16);
        unsigned hi = f32_to_bf16_rne(x4.z) | (f32_to_bf16_rne(x4.w) << 16);
        int r = (4 * p4) >> 7, k = (4 * p4) & 127;
        *(unsigned long long*)&XL[r * 136 + k] =
            (unsigned long long)lo | ((unsigned long long)hi << 32);
    }
    __syncthreads();

    const int w = t >> 6, l = t & 63, m = l & 15, q = l >> 4;
    f32x4 acc0 = {0.f, 0.f, 0.f, 0.f}, acc1 = {0.f, 0.f, 0.f, 0.f};
    #pragma unroll
    for (int ks = 0; ks < 4; ++ks) {
        s16x8 af = *(const s16x8*)&XL[m * 136 + ks * 32 + q * 8];
        s16x8 b0 = *(const s16x8*)&WL[(w * 32 + m) * 136 + ks * 32 + q * 8];
        s16x8 b1 = *(const s16x8*)&WL[(w * 32 + 16 + m) * 136 + ks * 32 + q * 8];
        acc0 = __builtin_amdgcn_mfma_f32_16x16x32_bf16(af, b0, acc0, 0, 0, 0);
        acc1 = __builtin_amdgcn_mfma_f32_16x16x32_bf16(af, b1, acc1, 0, 0, 0);
    }
    // C/D: col = m (= output feature within fblk), row = q*4+reg (= i in tile)
    #pragma unroll
    for (int j2 = 0; j2 < 2; ++j2) {
        const int fblk = 2 * w + j2;
        f32x4 acc = j2 ? acc1 : acc0;
        #pragma unroll
        for (int reg = 0; reg < 4; ++reg) {
            float v = acc[reg];
            int row_g = i0 + q * 4 + reg;           // Wx row (K2's j index)
            int kl = row_g & 31, jblk = row_g >> 5;
            wxb[(((jblk * 8 + fblk) * 64 + (kl >> 3) * 16 + m) << 3) + (kl & 7)] =
                (unsigned short)f32_to_bf16_rne(v);
            WxF[(q * 4 + reg) * 132 + fblk * 16 + m] = v;
        }
    }
    __syncthreads();
    if (t < 64) {
        int r = t >> 2, h = t & 3;
        float s_i = 0.f, s_j = 0.f;
        const float* ar = a + h * 64;
        #pragma unroll
        for (int d = 0; d < 32; ++d) {
            float wv = WxF[r * 132 + h * 32 + d];
            s_i += wv * ar[d];
            s_j += wv * ar[32 + d];
        }
        ai_s[(i0 + r) * 4 + h] = s_i * LOG2E;
        ajT_s[h * NN + i0 + r] = s_j * LOG2E;
    }
}

// ---------------------------------------------------------------------------
// K2: flash-style masked softmax + PV + residual + LayerNorm.
// grid=256 blocks (16 rows each), 1024 threads = 16 waves = (head h, parity p
// in 0..3) -> 4 waves/SIMD for latency hiding.  adjacency bits (8.4 KB) and
// ajT (64 KB, all heads) staged in LDS with coalesced loads; k-loop has zero
// scattered VMEM: 1 ds_read_b32 + 2 ds_read_b128 + 2 coalesced global dwordx4
// (wxb, L2-resident) + 2 MFMA per 32-j step.
// ---------------------------------------------------------------------------
__global__ __launch_bounds__(1024, 4) void k2_attn(
        const float* __restrict__ x,
        const unsigned* __restrict__ adjbits,
        const unsigned short* __restrict__ wxb,
        const float* __restrict__ ai_s,
        const float* __restrict__ ajT_s,
        const float* __restrict__ gamma,
        const float* __restrict__ beta,
        float* __restrict__ out) {
    __shared__ float ajL[4][4096];       // 64 KB
    __shared__ unsigned maskL[16][132];  // 8.4 KB, stride 132 -> 2-way (free)
    __shared__ float C_lds[4][16][32];   // 8 KB
    __shared__ float l_lds[4][16];

    const int t = threadIdx.x;
    const int i0 = blockIdx.x * 16;
    const int w = t >> 6, l = t & 63;
    const int h = w & 3, p = w >> 2;     // p in 0..3
    const int m = l & 15, q = l >> 4;

    // stage ajT: 16384 floats = 4096 f32x4, 4 per thread, coalesced
    {
        const f32x4* src = (const f32x4*)ajT_s;
        f32x4* dst = (f32x4*)&ajL[0][0];
        #pragma unroll
        for (int g = 0; g < 4; ++g) dst[t + 1024 * g] = src[t + 1024 * g];
    }
    // stage adjacency bits: 16 rows x 128 words (contiguous 8 KB), 2/thread
    {
        #pragma unroll
        for (int g = 0; g < 2; ++g) {
            int idx = t + 1024 * g;
            int r = idx >> 7, c = idx & 127;
            maskL[r][c] = adjbits[(long)(i0 + r) * 128 + c];
        }
    }
    const float ai = ai_s[(i0 + m) * 4 + h];
    __syncthreads();

    const unsigned short* bp = wxb + ((2 * h) * 64 + l) * 8;
    const float* ajh = &ajL[h][0] + q * 8;

    f32x4 acc0 = {0.f, 0.f, 0.f, 0.f}, acc1 = {0.f, 0.f, 0.f, 0.f};
    float lpart = 0.f;

    for (int ks = p; ks < 128; ks += 4) {   // 32 j per step, 32 iters/wave
        unsigned mq = (maskL[m][ks] >> (q * 8)) & 0xffu;  // bits for j=ks*32+q*8+e
        f32x4 aj0 = *(const f32x4*)(ajh + ks * 32);
        f32x4 aj1 = *(const f32x4*)(ajh + ks * 32 + 4);
        s16x8 b0 = *(const s16x8*)(bp + ks * 4096);
        s16x8 b1 = *(const s16x8*)(bp + ks * 4096 + 512);

        float ev[8];
        #pragma unroll
        for (int e = 0; e < 8; ++e) {
            float s = ai + (e < 4 ? aj0[e] : aj1[e - 4]);   // already * log2e
            s = fmaxf(s, SLOPE * s);                        // lrelu (scale-inv)
            float ex = __builtin_amdgcn_exp2f(s);
            ex = ((mq >> e) & 1u) ? ex : 0.0f;
            lpart += ex;
            ev[e] = ex;
        }
        union { s16x8 v; unsigned u[4]; } af;
        #pragma unroll
        for (int pr = 0; pr < 4; ++pr) {
            unsigned e0 = __builtin_bit_cast(unsigned, ev[2 * pr]);
            unsigned e1 = __builtin_bit_cast(unsigned, ev[2 * pr + 1]);
            af.u[pr] = __builtin_amdgcn_perm(e1, e0, 0x07060302);  // {hi16,hi16}
        }
        acc0 = __builtin_amdgcn_mfma_f32_16x16x32_bf16(af.v, b0, acc0, 0, 0, 0);
        acc1 = __builtin_amdgcn_mfma_f32_16x16x32_bf16(af.v, b1, acc1, 0, 0, 0);
    }

    // row-sum l across the 4 quads (lanes l, l^16, l^32, l^48 share row m)
    lpart += __shfl_xor(lpart, 16, 64);
    lpart += __shfl_xor(lpart, 32, 64);

    // combine the 4 parity partials (deterministic sequential accumulate)
    if (p == 0) {
        #pragma unroll
        for (int reg = 0; reg < 4; ++reg) {
            C_lds[h][q * 4 + reg][m] = acc0[reg];
            C_lds[h][q * 4 + reg][16 + m] = acc1[reg];
        }
        if (l < 16) l_lds[h][l] = lpart;
    }
    __syncthreads();
    if (p == 1) {
        #pragma unroll
        for (int reg = 0; reg < 4; ++reg) {
            C_lds[h][q * 4 + reg][m] += acc0[reg];
            C_lds[h][q * 4 + reg][16 + m] += acc1[reg];
        }
        if (l < 16) l_lds[h][l] += lpart;
    }
    __syncthreads();
    if (p == 2) {
        #pragma unroll
        for (int reg = 0; reg < 4; ++reg) {
            C_lds[h][q * 4 + reg][m] += acc0[reg];
            C_lds[h][q * 4 + reg][16 + m] += acc1[reg];
        }
        if (l < 16) l_lds[h][l] += lpart;
    }
    __syncthreads();
    if (p == 3) {
        #pragma unroll
        for (int reg = 0; reg < 4; ++reg) {
            C_lds[h][q * 4 + reg][m] += acc0[reg];
            C_lds[h][q * 4 + reg][16 + m] += acc1[reg];
        }
        if (l < 16) l_lds[h][l] += lpart;
    }
    __syncthreads();

    // epilogue: normalize, residual, LayerNorm.  32 threads/row, rows 0..15.
    if (t < 512) {
        const int r = t >> 5, c32 = t & 31;
        const int f0 = c32 * 4;
        const int hh = f0 >> 5, cl = f0 & 31;
        const float linv = 1.0f / l_lds[hh][r];
        f32x4 xv = *(const f32x4*)(x + (long)(i0 + r) * 128 + f0);
        float y[4], s1 = 0.f, s2 = 0.f;
        #pragma unroll
        for (int kk = 0; kk < 4; ++kk) {
            float yy = C_lds[hh][r][cl + kk] * linv + xv[kk];
            y[kk] = yy; s1 += yy; s2 += yy * yy;
        }
        #pragma unroll
        for (int s = 1; s <= 16; s <<= 1) {
            s1 += __shfl_xor(s1, s, 64);
            s2 += __shfl_xor(s2, s, 64);
        }
        const float mean = s1 * (1.0f / 128.0f);
        const float var = s2 * (1.0f / 128.0f) - mean * mean;
        const float rstd = rsqrtf(var + 1e-5f);
        f32x4 gv = *(const f32x4*)(gamma + f0);
        f32x4 bv = *(const f32x4*)(beta + f0);
        f32x4 ov;
        #pragma unroll
        for (int kk = 0; kk < 4; ++kk)
            ov[kk] = gv[kk] * ((y[kk] - mean) * rstd) + bv[kk];
        *(f32x4*)(out + (long)(i0 + r) * 128 + f0) = ov;
    }
}

extern "C" void kernel_launch(void* const* d_in, const int* in_sizes, int n_in,
                              void* d_out, int out_size, void* d_ws, size_t ws_size,
                              hipStream_t stream) {
    const float* x = (const float*)d_in[0];
    const unsigned* adj_raw = (const unsigned*)d_in[1];  // bool-as-uint8 OR int32
    const float* W = (const float*)d_in[2];
    const float* a = (const float*)d_in[3];
    const float* gamma = (const float*)d_in[4];
    const float* beta = (const float*)d_in[5];

    unsigned short* wxb = (unsigned short*)d_ws;                        // 1 MB
    float* ai_s = (float*)((char*)d_ws + (1 << 20));                    // 64 KB
    float* ajT_s = (float*)((char*)d_ws + (1 << 20) + (64 << 10));      // 64 KB
    unsigned* adjbits = (unsigned*)((char*)d_ws + (2 << 20));           // 2 MB

    k0_pack<<<2048, 256, 0, stream>>>(adj_raw, adjbits);
    k1_wx<<<256, 256, 0, stream>>>(x, W, a, wxb, ai_s, ajT_s);
    k2_attn<<<256, 1024, 0, stream>>>(x, adjbits, wxb, ai_s, ajT_s, gamma, beta,
                                      (float*)d_out);
}

// Round 4
// 135.431 us; speedup vs baseline: 1.1092x; 1.0071x over previous
//
#include <hip/hip_runtime.h>
#include <hip/hip_bf16.h>
#include <stdint.h>

#define NN 4096
#define SLOPE 0.2f
#define LOG2E 1.44269504088896340736f

typedef float f32x4 __attribute__((ext_vector_type(4)));
typedef short s16x8 __attribute__((ext_vector_type(8)));
typedef unsigned u32x4 __attribute__((ext_vector_type(4)));

static __device__ __forceinline__ unsigned f32_to_bf16_rne(float f) {
    unsigned u = __builtin_bit_cast(unsigned, f);
    return (u + 0x7FFFu + ((u >> 16) & 1u)) >> 16;
}

// ---------------------------------------------------------------------------
// K01: fused adjacency-pack (blocks 0..2047) + Wx GEMM (blocks 2048..2303).
// Pack path is HBM-streaming; Wx path is MFMA — they overlap on the device.
// wxb8: Wx in fp8 e4m3, tiled [jblk(128)][h(4)][lane(64)][16B]: lane
// (qp=l>>4, n=l&15) holds B[k=qp*8+e][n] for col-group0 (bytes 0-7) and
// col-group1 (bytes 8-15) of head h's 32 columns.
// ---------------------------------------------------------------------------
__global__ __launch_bounds__(256) void k01(const unsigned* __restrict__ adj_raw,
                                           const float* __restrict__ x,
                                           const float* __restrict__ W,
                                           const float* __restrict__ a,
                                           unsigned* __restrict__ bits,
                                           unsigned* __restrict__ wxb8,
                                           float* __restrict__ ai_s,
                                           float* __restrict__ ajT_s) {
    const int t = threadIdx.x;
    if (blockIdx.x < 2048) {
        // ---- adjacency pack path (dtype auto-detect, verified R2/R3) ----
        __shared__ int s_i32;
        if (t == 0) {
            int all_small = 1;
            for (int i = 0; i < 32; ++i) all_small &= (adj_raw[i] <= 1u);
            s_i32 = all_small;
        }
        __syncthreads();
        const long o = (long)blockIdx.x * 256 + t;
        unsigned mm = 0;
        if (s_i32) {
            const u32x4* p = (const u32x4*)adj_raw + o * 8;  // 32 ints
            #pragma unroll
            for (int g = 0; g < 8; ++g) {
                u32x4 v = p[g];
                mm |= (v.x & 1u) << (g * 4) | (v.y & 1u) << (g * 4 + 1) |
                      (v.z & 1u) << (g * 4 + 2) | (v.w & 1u) << (g * 4 + 3);
            }
        } else {
            const u32x4* p = (const u32x4*)adj_raw + o * 2;  // 32 bytes
            #pragma unroll
            for (int g = 0; g < 2; ++g) {
                u32x4 v = p[g];
                unsigned d[4] = {v.x, v.y, v.z, v.w};
                #pragma unroll
                for (int qq = 0; qq < 4; ++qq)
                    #pragma unroll
                    for (int b = 0; b < 4; ++b)
                        mm |= ((d[qq] >> (8 * b)) & 1u) << (g * 16 + qq * 4 + b);
            }
        }
        bits[o] = mm;
        return;
    }

    // ---- Wx path ----
    __shared__ unsigned short WL[128 * 136];
    __shared__ unsigned short XL[16 * 136];
    __shared__ float WxF[16 * 132];

    const int bid = blockIdx.x - 2048;
    const int i0 = bid * 16;

    for (int p4 = t; p4 < 4096; p4 += 256) {
        f32x4 w4 = *(const f32x4*)(W + 4 * p4);
        unsigned lo = f32_to_bf16_rne(w4.x) | (f32_to_bf16_rne(w4.y) << 16);
        unsigned hi = f32_to_bf16_rne(w4.z) | (f32_to_bf16_rne(w4.w) << 16);
        int c = (4 * p4) >> 7, k = (4 * p4) & 127;
        *(unsigned long long*)&WL[c * 136 + k] =
            (unsigned long long)lo | ((unsigned long long)hi << 32);
    }
    for (int p4 = t; p4 < 512; p4 += 256) {
        f32x4 x4 = *(const f32x4*)(x + (long)i0 * 128 + 4 * p4);
        unsigned lo = f32_to_bf16_rne(x4.x) | (f32_to_bf16_rne(x4.y) << 16);
        unsigned hi = f32_to_bf16_rne(x4.z) | (f32_to_bf16_rne(x4.w) << 16);
        int r = (4 * p4) >> 7, k = (4 * p4) & 127;
        *(unsigned long long*)&XL[r * 136 + k] =
            (unsigned long long)lo | ((unsigned long long)hi << 32);
    }
    __syncthreads();

    const int w = t >> 6, l = t & 63, m = l & 15, q = l >> 4;
    f32x4 acc0 = {0.f, 0.f, 0.f, 0.f}, acc1 = {0.f, 0.f, 0.f, 0.f};
    #pragma unroll
    for (int ks = 0; ks < 4; ++ks) {
        s16x8 af = *(const s16x8*)&XL[m * 136 + ks * 32 + q * 8];
        s16x8 b0 = *(const s16x8*)&WL[(w * 32 + m) * 136 + ks * 32 + q * 8];
        s16x8 b1 = *(const s16x8*)&WL[(w * 32 + 16 + m) * 136 + ks * 32 + q * 8];
        acc0 = __builtin_amdgcn_mfma_f32_16x16x32_bf16(af, b0, acc0, 0, 0, 0);
        acc1 = __builtin_amdgcn_mfma_f32_16x16x32_bf16(af, b1, acc1, 0, 0, 0);
    }
    // C/D: col = m, row = q*4+reg.  Rows i0..i0+15 -> kk = (i0&16)+q*4+reg,
    // jblk = i0>>5; the 4 regs are 4 consecutive fp8 bytes -> 1 dword store.
    const int jblk = i0 >> 5;
    const int qp = ((i0 & 16) + q * 4) >> 3;
    const int ehalf = q & 1;  // kk&7 in {0..3} (q even) or {4..7} (q odd)
    #pragma unroll
    for (int j2 = 0; j2 < 2; ++j2) {
        f32x4 acc = j2 ? acc1 : acc0;
        unsigned u = (unsigned)__builtin_amdgcn_cvt_pk_fp8_f32(acc[0], acc[1], 0, false);
        u = (unsigned)__builtin_amdgcn_cvt_pk_fp8_f32(acc[2], acc[3], (int)u, true);
        wxb8[(((jblk * 4 + w) * 64 + qp * 16 + m) << 2) + j2 * 2 + ehalf] = u;
        #pragma unroll
        for (int reg = 0; reg < 4; ++reg)
            WxF[(q * 4 + reg) * 132 + (2 * w + j2) * 16 + m] = acc[reg];
    }
    __syncthreads();
    if (t < 64) {
        int r = t >> 2, h = t & 3;
        float s_i = 0.f, s_j = 0.f;
        const float* ar = a + h * 64;
        #pragma unroll
        for (int d = 0; d < 32; ++d) {
            float wv = WxF[r * 132 + h * 32 + d];
            s_i += wv * ar[d];
            s_j += wv * ar[32 + d];
        }
        ai_s[(i0 + r) * 4 + h] = s_i * LOG2E;
        ajT_s[h * NN + i0 + r] = s_j * LOG2E;
    }
}

// ---------------------------------------------------------------------------
// K2: flash-style masked softmax + PV + residual + LayerNorm.
// 256 blocks x 1024 threads (16 waves = head h x parity p, 4 waves/SIMD).
// P in bf8 e5m2 (range 2^15 -> no max-subtract needed), Wx in fp8 e4m3:
// mfma_f32_16x16x32_bf8_fp8.  One dwordx4 B-load per 32-j step (prefetched);
// row-sum l computed by a third MFMA against an all-ones e4m3 B.
// ---------------------------------------------------------------------------
__global__ __launch_bounds__(1024, 4) void k2_attn(
        const float* __restrict__ x,
        const unsigned* __restrict__ adjbits,
        const unsigned* __restrict__ wxb8,
        const float* __restrict__ ai_s,
        const float* __restrict__ ajT_s,
        const float* __restrict__ gamma,
        const float* __restrict__ beta,
        float* __restrict__ out) {
    __shared__ float ajL[4][4096];       // 64 KB
    __shared__ unsigned maskL[16][132];  // 8.4 KB (stride 132 -> 2-way, free)
    __shared__ float C_lds[4][16][32];   // 8 KB
    __shared__ float l_lds[4][16];

    const int t = threadIdx.x;
    const int i0 = blockIdx.x * 16;
    const int w = t >> 6, l = t & 63;
    const int h = w & 3, p = w >> 2;     // p in 0..3
    const int m = l & 15, q = l >> 4;

    {   // stage ajT (all 4 heads), coalesced f32x4
        const f32x4* src = (const f32x4*)ajT_s;
        f32x4* dst = (f32x4*)&ajL[0][0];
        #pragma unroll
        for (int g = 0; g < 4; ++g) dst[t + 1024 * g] = src[t + 1024 * g];
    }
    {   // stage adjacency bitmask rows i0..i0+15
        #pragma unroll
        for (int g = 0; g < 2; ++g) {
            int idx = t + 1024 * g;
            int r = idx >> 7, c = idx & 127;
            maskL[r][c] = adjbits[(long)(i0 + r) * 128 + c];
        }
    }
    const float ai = ai_s[(i0 + m) * 4 + h];
    __syncthreads();

    const unsigned* bp8 = wxb8 + ((h * 64 + l) << 2);  // 16 B per lane
    const float* ajh = &ajL[h][0] + q * 8;
    const long ONESB = 0x3838383838383838L;            // e4m3 1.0 x8

    f32x4 acc0 = {0.f, 0.f, 0.f, 0.f}, acc1 = {0.f, 0.f, 0.f, 0.f};
    f32x4 accl = {0.f, 0.f, 0.f, 0.f};

    u32x4 bv = *(const u32x4*)(bp8 + (p << 10));
    for (int ks = p; ks < 128; ks += 4) {   // 32 j per step, 32 iters/wave
        const int ksn = (ks + 4 < 128) ? (ks + 4) : ks;
        u32x4 bvn = *(const u32x4*)(bp8 + (ksn << 10));  // prefetch next

        unsigned mq = (maskL[m][ks] >> (q * 8)) & 0xffu;
        f32x4 aj0 = *(const f32x4*)(ajh + ks * 32);
        f32x4 aj1 = *(const f32x4*)(ajh + ks * 32 + 4);

        float ev[8];
        #pragma unroll
        for (int e = 0; e < 8; ++e) {
            float s = ai + (e < 4 ? aj0[e] : aj1[e - 4]);   // already * log2e
            s = fmaxf(s, SLOPE * s);                        // lrelu (scale-inv)
            float ex = __builtin_amdgcn_exp2f(s);
            ev[e] = ((mq >> e) & 1u) ? ex : 0.0f;
        }
        unsigned d0 = (unsigned)__builtin_amdgcn_cvt_pk_bf8_f32(ev[0], ev[1], 0, false);
        d0 = (unsigned)__builtin_amdgcn_cvt_pk_bf8_f32(ev[2], ev[3], (int)d0, true);
        unsigned d1 = (unsigned)__builtin_amdgcn_cvt_pk_bf8_f32(ev[4], ev[5], 0, false);
        d1 = (unsigned)__builtin_amdgcn_cvt_pk_bf8_f32(ev[6], ev[7], (int)d1, true);
        long av = (long)(((unsigned long long)d1 << 32) | d0);
        long b0 = (long)(((unsigned long long)bv.y << 32) | bv.x);
        long b1 = (long)(((unsigned long long)bv.w << 32) | bv.z);

        acc0 = __builtin_amdgcn_mfma_f32_16x16x32_bf8_fp8(av, b0, acc0, 0, 0, 0);
        acc1 = __builtin_amdgcn_mfma_f32_16x16x32_bf8_fp8(av, b1, acc1, 0, 0, 0);
        accl = __builtin_amdgcn_mfma_f32_16x16x32_bf8_fp8(av, ONESB, accl, 0, 0, 0);
        bv = bvn;
    }

    // combine the 4 parity partials (C/D layout: row=q*4+reg, col=m;
    // accl rows hold l_{q*4+reg}, identical across m -> m==0 writes)
    if (p == 0) {
        #pragma unroll
        for (int reg = 0; reg < 4; ++reg) {
            C_lds[h][q * 4 + reg][m] = acc0[reg];
            C_lds[h][q * 4 + reg][16 + m] = acc1[reg];
            if (m == 0) l_lds[h][q * 4 + reg] = accl[reg];
        }
    }
    __syncthreads();
    if (p == 1) {
        #pragma unroll
        for (int reg = 0; reg < 4; ++reg) {
            C_lds[h][q * 4 + reg][m] += acc0[reg];
            C_lds[h][q * 4 + reg][16 + m] += acc1[reg];
            if (m == 0) l_lds[h][q * 4 + reg] += accl[reg];
        }
    }
    __syncthreads();
    if (p == 2) {
        #pragma unroll
        for (int reg = 0; reg < 4; ++reg) {
            C_lds[h][q * 4 + reg][m] += acc0[reg];
            C_lds[h][q * 4 + reg][16 + m] += acc1[reg];
            if (m == 0) l_lds[h][q * 4 + reg] += accl[reg];
        }
    }
    __syncthreads();
    if (p == 3) {
        #pragma unroll
        for (int reg = 0; reg < 4; ++reg) {
            C_lds[h][q * 4 + reg][m] += acc0[reg];
            C_lds[h][q * 4 + reg][16 + m] += acc1[reg];
            if (m == 0) l_lds[h][q * 4 + reg] += accl[reg];
        }
    }
    __syncthreads();

    // epilogue: normalize, residual, LayerNorm.  32 threads/row.
    if (t < 512) {
        const int r = t >> 5, c32 = t & 31;
        const int f0 = c32 * 4;
        const int hh = f0 >> 5, cl = f0 & 31;
        const float linv = 1.0f / l_lds[hh][r];
        f32x4 xv = *(const f32x4*)(x + (long)(i0 + r) * 128 + f0);
        float y[4], s1 = 0.f, s2 = 0.f;
        #pragma unroll
        for (int kk = 0; kk < 4; ++kk) {
            float yy = C_lds[hh][r][cl + kk] * linv + xv[kk];
            y[kk] = yy; s1 += yy; s2 += yy * yy;
        }
        #pragma unroll
        for (int s = 1; s <= 16; s <<= 1) {
            s1 += __shfl_xor(s1, s, 64);
            s2 += __shfl_xor(s2, s, 64);
        }
        const float mean = s1 * (1.0f / 128.0f);
        const float var = s2 * (1.0f / 128.0f) - mean * mean;
        const float rstd = rsqrtf(var + 1e-5f);
        f32x4 gv = *(const f32x4*)(gamma + f0);
        f32x4 bv2 = *(const f32x4*)(beta + f0);
        f32x4 ov;
        #pragma unroll
        for (int kk = 0; kk < 4; ++kk)
            ov[kk] = gv[kk] * ((y[kk] - mean) * rstd) + bv2[kk];
        *(f32x4*)(out + (long)(i0 + r) * 128 + f0) = ov;
    }
}

extern "C" void kernel_launch(void* const* d_in, const int* in_sizes, int n_in,
                              void* d_out, int out_size, void* d_ws, size_t ws_size,
                              hipStream_t stream) {
    const float* x = (const float*)d_in[0];
    const unsigned* adj_raw = (const unsigned*)d_in[1];
    const float* W = (const float*)d_in[2];
    const float* a = (const float*)d_in[3];
    const float* gamma = (const float*)d_in[4];
    const float* beta = (const float*)d_in[5];

    unsigned* wxb8 = (unsigned*)d_ws;                                   // 512 KB
    float* ai_s = (float*)((char*)d_ws + (512 << 10));                  // 64 KB
    float* ajT_s = (float*)((char*)d_ws + (576 << 10));                 // 64 KB
    unsigned* adjbits = (unsigned*)((char*)d_ws + (1 << 20));           // 2 MB

    k01<<<2304, 256, 0, stream>>>(adj_raw, x, W, a, adjbits, wxb8, ai_s, ajT_s);
    k2_attn<<<256, 1024, 0, stream>>>(x, adjbits, wxb8, ai_s, ajT_s, gamma, beta,
                                      (float*)d_out);
}